// Round 10
// baseline (137.763 us; speedup 1.0000x reference)
//
#include <hip/hip_runtime.h>
#include <hip/hip_bf16.h>

// Problem constants
#define BB 16
#define SS 1024
#define DD 384
#define HH 6
#define KK 9
#define KH 54      // K*H
#define OUTD 384
#define NKT 12     // K-steps: 384/32
#define VLD 392    // LDS leading dim (bf16): 784 B/row -> 4-bank shift/row, <=2-way (free)
#define RPB 32     // rows (seq positions) per block
#define NTH 512    // threads per block (8 waves)

typedef __attribute__((ext_vector_type(4))) float floatx4;
typedef __attribute__((ext_vector_type(8))) __bf16 bf16x8;
typedef __attribute__((ext_vector_type(4))) __bf16 bf16x4;

// ---------------------------------------------------------------------------
// Kernel 0: cast + swizzle weights into MFMA B-fragment order (unchanged).
// WkT: 4 ntiles (54 rows zero-padded to 64) x 12 ksteps x 64 lanes x 8 bf16.
// WpT: 24 ntiles x 12 ksteps x 64 lanes x 8 bf16.
// ---------------------------------------------------------------------------
__global__ __launch_bounds__(256) void cast_kernel(const float* __restrict__ Wk,
                                                   const float* __restrict__ Wp,
                                                   __bf16* __restrict__ WkT,
                                                   __bf16* __restrict__ WpT) {
    int i = blockIdx.x * 256 + threadIdx.x;
    if (i < 4 * NKT * 64 * 8) {                    // 24576 elems of WkT
        int e = i & 7, lane = (i >> 3) & 63, t = i >> 9;
        int kstep = t % NKT, ntile = t / NKT;
        int row = ntile * 16 + (lane & 15);
        int col = kstep * 32 + ((lane >> 4) << 3) + e;
        WkT[i] = (row < KH) ? (__bf16)Wk[row * DD + col] : (__bf16)0.0f;
    } else if (i < 24576 + 24 * NKT * 64 * 8) {    // 147456 elems of WpT
        int j = i - 24576;
        int e = j & 7, lane = (j >> 3) & 63, t = j >> 9;
        int kstep = t % NKT, ntile = t / NKT;
        int row = ntile * 16 + (lane & 15);
        int col = kstep * 32 + ((lane >> 4) << 3) + e;
        WpT[j] = (__bf16)Wp[row * DD + col];
    }
}

// ---------------------------------------------------------------------------
// Kernel 1: EXACTLY the round-3 kernel that PASSED (absmax 3.9e-3), with ONE
// delta: __launch_bounds__(512,8) -> (512,4). R3's counters showed VGPR=32
// (the ,8 bound strangled the allocator; aR[6]+bfr[2][3]+acc[2][3]+qv/kv/vpre
// all spilled to scratch -> 45 us fused). With cap 128 the register state
// fits. No other changes — clean attribution.
// Structure (R3, hardware-validated): no qk LDS staging (q*ks A-fragments
// straight from global), dk in-place in lgS, conv to registers, A written
// over dead v rows, acc[2][3] phase 5 with WpT prologue prefetch.
// LDS: vS 40*VLD*2 = 31360 + lgS 32*66*4 = 8448 = 39808 B.
// ---------------------------------------------------------------------------
__global__ __launch_bounds__(NTH, 4) void fused_kernel(const float* __restrict__ q,
                                                       const float* __restrict__ ks,
                                                       const float* __restrict__ v,
                                                       const __bf16* __restrict__ WkT,
                                                       const float* __restrict__ bk,
                                                       const __bf16* __restrict__ WpT,
                                                       const float* __restrict__ bp,
                                                       float* __restrict__ out) {
    __shared__ __bf16 vS[40 * VLD];                // 31360 B: v window rows 0..39; later A rows 0..31
    __shared__ float  lgS[RPB * 66];               //  8448 B: logits, then dk in-place

    const int tid  = threadIdx.x;
    const int wave = tid >> 6;
    const int lane = tid & 63;
    const int m0   = blockIdx.x * RPB;
    const int b    = blockIdx.x >> 5;              // 32 blocks per batch
    const int s0   = (blockIdx.x & 31) * RPB;
    const int fr   = lane & 15;
    const int fk   = (lane >> 4) * 8;
    const int col_in = lane & 15;
    const int rgrp   = (lane >> 4) * 4;

    // ---- P0: v window (rows s0-4..s0+35) -> bf16 -> LDS rows 0..39.
    //      No barrier before P1: P1 touches only global + registers. ----
    {
        const float* vb = v + (size_t)b * SS * DD;
#pragma unroll
        for (int it = 0; it < 8; ++it) {
            int c = tid + it * NTH;                // 0..4095 (3840 live)
            if (c < 3840) {
                int row = c / 96, col = (c % 96) * 4;
                int r = s0 + row - 4;
                int rc = r < 0 ? 0 : (r > SS - 1 ? SS - 1 : r);
                floatx4 val = *reinterpret_cast<const floatx4*>(vb + (size_t)rc * DD + col);
                if (r < 0 || r >= SS) val = floatx4{0.0f, 0.0f, 0.0f, 0.0f};
                bf16x4 vk4 = { (__bf16)val.x, (__bf16)val.y, (__bf16)val.z, (__bf16)val.w };
                *reinterpret_cast<bf16x4*>(&vS[row * VLD + col]) = vk4;
            }
        }
    }

    // ---- P1: logits MFMA. wave=(rt,nt). A-fragments of qk loaded straight
    //      from global: lane (fr,kq) reads q/ks row m0+rt*16+fr, cols
    //      s*32+fk..+7 -> per wave-load 16 rows x 64 B, fully coalesced. ----
    {
        const int rt = wave >> 2;
        const int nt = wave & 3;
        const float* qrow = q  + (size_t)(m0 + rt * 16 + fr) * DD + fk;
        const float* krow = ks + (size_t)(m0 + rt * 16 + fr) * DD + fk;
        const __bf16* wkb = WkT + (((nt * NKT) * 64 + lane) << 3);
        bf16x8 wf0 = *reinterpret_cast<const bf16x8*>(wkb);
        bf16x8 wf1;
        floatx4 acc = {};
#pragma unroll
        for (int s = 0; s < NKT; ++s) {
            if (s + 1 < NKT) {
                const __bf16* nb = wkb + ((size_t)(s + 1) << 9);
                if ((s & 1) == 0) wf1 = *reinterpret_cast<const bf16x8*>(nb);
                else              wf0 = *reinterpret_cast<const bf16x8*>(nb);
            }
            floatx4 q0 = *reinterpret_cast<const floatx4*>(qrow + s * 32);
            floatx4 q1 = *reinterpret_cast<const floatx4*>(qrow + s * 32 + 4);
            floatx4 k0 = *reinterpret_cast<const floatx4*>(krow + s * 32);
            floatx4 k1 = *reinterpret_cast<const floatx4*>(krow + s * 32 + 4);
            floatx4 p0 = q0 * k0, p1 = q1 * k1;
            bf16x8 af = { (__bf16)p0.x, (__bf16)p0.y, (__bf16)p0.z, (__bf16)p0.w,
                          (__bf16)p1.x, (__bf16)p1.y, (__bf16)p1.z, (__bf16)p1.w };
            acc = __builtin_amdgcn_mfma_f32_16x16x32_bf16(
                af, (s & 1) == 0 ? wf0 : wf1, acc, 0, 0, 0);
        }
        // C/D layout: col = lane&15, row = (lane>>4)*4 + reg
#pragma unroll
        for (int r = 0; r < 4; ++r)
            lgS[(rt * 16 + rgrp + r) * 66 + nt * 16 + col_in] = acc[r];
    }
    __syncthreads();                               // B1: logits + v-spill complete

    // ---- P2: softmax over 9 taps, dk written IN-PLACE over lgS ----
    if (tid < RPB * HH) {
        int row = tid / HH, h = tid % HH;
        float lg[KK];
        float mx = -1e30f;
#pragma unroll
        for (int k = 0; k < KK; ++k) {
            float s = lgS[row * 66 + h * KK + k] + bk[h * KK + k];
            lg[k] = s;
            mx = fmaxf(mx, s);
        }
        float sum = 0.0f;
#pragma unroll
        for (int k = 0; k < KK; ++k) { lg[k] = __expf(lg[k] - mx); sum += lg[k]; }
        float inv = 1.0f / sum;
#pragma unroll
        for (int k = 0; k < KK; ++k) lgS[row * 66 + h * KK + k] = lg[k] * inv;
    }
    __syncthreads();                               // B2: dk ready

    // ---- P3: 9-tap conv into REGISTERS (reads vS rows 0..39 + dk) ----
    bf16x4 aR[6];
#pragma unroll
    for (int it = 0; it < 6; ++it) {
        int p = tid + it * NTH;                    // 0..3071 = 32 rows x 96 chunks
        int row = p / 96, c4 = p % 96;
        int h = c4 >> 4;
        const float* dkr = &lgS[row * 66 + h * KK];
        floatx4 a = {};
#pragma unroll
        for (int k = 0; k < KK; ++k) {
            bf16x4 w = *reinterpret_cast<const bf16x4*>(&vS[(row + k) * VLD + c4 * 4]);
            floatx4 wf = { (float)w[0], (float)w[1], (float)w[2], (float)w[3] };
            a += wf * dkr[k];
        }
        aR[it] = bf16x4{ (__bf16)a.x, (__bf16)a.y, (__bf16)a.z, (__bf16)a.w };
    }

    // issue WpT kstep-0 fragments now (read-only; latency spans two barriers)
    const int nt0 = wave * 3;
    const __bf16* wpb = WpT + (((nt0 * NKT) * 64 + lane) << 3);
    bf16x8 bfr[2][3];
#pragma unroll
    for (int j = 0; j < 3; ++j)
        bfr[0][j] = *reinterpret_cast<const bf16x8*>(wpb + ((size_t)(j * NKT) << 9));

    __syncthreads();                               // B3: all conv reads of vS done

    // ---- P4: write A (bf16) over dead v rows 0..31 ----
#pragma unroll
    for (int it = 0; it < 6; ++it) {
        int p = tid + it * NTH;
        int row = p / 96, c4 = p % 96;
        *reinterpret_cast<bf16x4*>(&vS[row * VLD + c4 * 4]) = aR[it];
    }
    __syncthreads();                               // B4: A ready

    // ---- P5: C = A @ Wp^T + bp, 2-deep rolling B prefetch, acc[2][3] ----
    {
        floatx4 acc[2][3] = {};
#pragma unroll
        for (int s = 0; s < NKT; ++s) {
            const int cur = s & 1, nxt = cur ^ 1;
            if (s + 1 < NKT) {
#pragma unroll
                for (int j = 0; j < 3; ++j)
                    bfr[nxt][j] = *reinterpret_cast<const bf16x8*>(
                        wpb + ((size_t)(j * NKT + s + 1) << 9));
            }
            bf16x8 a0 = *reinterpret_cast<const bf16x8*>(&vS[fr * VLD + s * 32 + fk]);
            bf16x8 a1 = *reinterpret_cast<const bf16x8*>(&vS[(16 + fr) * VLD + s * 32 + fk]);
#pragma unroll
            for (int j = 0; j < 3; ++j) {
                acc[0][j] = __builtin_amdgcn_mfma_f32_16x16x32_bf16(a0, bfr[cur][j], acc[0][j], 0, 0, 0);
                acc[1][j] = __builtin_amdgcn_mfma_f32_16x16x32_bf16(a1, bfr[cur][j], acc[1][j], 0, 0, 0);
            }
        }
        float* ob = out + (size_t)m0 * OUTD;
#pragma unroll
        for (int j = 0; j < 3; ++j) {
            int col = (nt0 + j) * 16 + col_in;
            float bv = bp[col];
#pragma unroll
            for (int rt = 0; rt < 2; ++rt)
#pragma unroll
                for (int r = 0; r < 4; ++r)
                    ob[(size_t)(rt * 16 + rgrp + r) * OUTD + col] = acc[rt][j][r] + bv;
        }
    }
}

// ---------------------------------------------------------------------------
extern "C" void kernel_launch(void* const* d_in, const int* in_sizes, int n_in,
                              void* d_out, int out_size, void* d_ws, size_t ws_size,
                              hipStream_t stream) {
    const float* q  = (const float*)d_in[0];
    const float* ks = (const float*)d_in[1];
    const float* v  = (const float*)d_in[2];
    const float* Wk = (const float*)d_in[3];
    const float* bk = (const float*)d_in[4];
    const float* Wp = (const float*)d_in[5];
    const float* bp = (const float*)d_in[6];
    float* out = (float*)d_out;

    // ws layout: WkT bf16 49152 B | WpT bf16 294912 B
    __bf16* WkT = (__bf16*)d_ws;
    __bf16* WpT = (__bf16*)((char*)d_ws + 49152);

    cast_kernel<<<(24576 + 147456 + 255) / 256, 256, 0, stream>>>(Wk, Wp, WkT, WpT);
    fused_kernel<<<(BB * SS) / RPB, NTH, 0, stream>>>(q, ks, v, WkT, bk, WpT, bp, out);
}